// Round 1
// baseline (440.019 us; speedup 1.0000x reference)
//
#include <hip/hip_runtime.h>
#include <hip/hip_bf16.h>

// ReadoutLayer: Wx = x @ W^T (+b cancels under BN), BatchNorm(train) over B*T,
// then ut = a*ut + (1-a)*wxn per t with acc += softmax(ut, axis=H).
// Decomposition: bf16-MFMA GEMM -> column stats -> chunked linear-recurrence
// scan (chunks of L=20 over T) -> per-chunk softmax accumulation -> reduce.

namespace {
constexpr int kB = 32;
constexpr int kT = 2000;
constexpr int kD = 512;
constexpr int kH = 512;
constexpr int kM = kB * kT;   // 64000 rows
constexpr int kL = 20;        // chunk length
constexpr int kC = kT / kL;   // 100 chunks per batch
constexpr float kALo = 0.81873075307798182f;  // exp(-1/5)
constexpr float kAHi = 0.96078943915232320f;  // exp(-1/25)

typedef __bf16 bf16x8 __attribute__((ext_vector_type(8)));
typedef float floatx4 __attribute__((ext_vector_type(4)));

// ---------- K1: GEMM Wx[r,h] = sum_d x[r,d] * W[h,d] (bf16 MFMA 16x16x32) ----------
// 64x64 block tile, 4 waves, each wave computes a 16-row strip (4 MFMA tiles).
__global__ __launch_bounds__(256) void gemm_k(const float* __restrict__ X,
                                              const float* __restrict__ Wm,
                                              float* __restrict__ Wx) {
  __shared__ __bf16 As[64][32];  // [m][k]
  __shared__ __bf16 Bs[64][32];  // [n][k] == W[col0+n][kk+k]
  const int tid = threadIdx.x;
  const size_t row0 = (size_t)blockIdx.x * 64;
  const int col0 = blockIdx.y * 64;
  const int wave = tid >> 6, lane = tid & 63;
  const int quad = lane >> 4, ln = lane & 15;
  const int srow = tid >> 2, sk = (tid & 3) * 8;

  floatx4 acc[4] = {};

  for (int kk = 0; kk < kD; kk += 32) {
    const float* pa = X + (row0 + srow) * kD + kk + sk;
    const float* pb = Wm + (size_t)(col0 + srow) * kD + kk + sk;
    const float4 a0 = *(const float4*)pa;
    const float4 a1 = *(const float4*)(pa + 4);
    const float4 b0 = *(const float4*)pb;
    const float4 b1 = *(const float4*)(pb + 4);
    bf16x8 av, bv;
    av[0] = (__bf16)a0.x; av[1] = (__bf16)a0.y; av[2] = (__bf16)a0.z; av[3] = (__bf16)a0.w;
    av[4] = (__bf16)a1.x; av[5] = (__bf16)a1.y; av[6] = (__bf16)a1.z; av[7] = (__bf16)a1.w;
    bv[0] = (__bf16)b0.x; bv[1] = (__bf16)b0.y; bv[2] = (__bf16)b0.z; bv[3] = (__bf16)b0.w;
    bv[4] = (__bf16)b1.x; bv[5] = (__bf16)b1.y; bv[6] = (__bf16)b1.z; bv[7] = (__bf16)b1.w;
    *(bf16x8*)&As[srow][sk] = av;
    *(bf16x8*)&Bs[srow][sk] = bv;
    __syncthreads();
    // a_frag: A[m=ln][k=quad*8+j]; b_frag: B[k=quad*8+j][n=ln]
    const bf16x8 af = *(const bf16x8*)&As[wave * 16 + ln][quad * 8];
#pragma unroll
    for (int nt = 0; nt < 4; ++nt) {
      const bf16x8 bf = *(const bf16x8*)&Bs[nt * 16 + ln][quad * 8];
      acc[nt] = __builtin_amdgcn_mfma_f32_16x16x32_bf16(af, bf, acc[nt], 0, 0, 0);
    }
    __syncthreads();
  }
  // C/D layout: col = lane&15, row = quad*4 + reg
#pragma unroll
  for (int nt = 0; nt < 4; ++nt)
#pragma unroll
    for (int r = 0; r < 4; ++r)
      Wx[(row0 + wave * 16 + quad * 4 + r) * kH + col0 + nt * 16 + ln] = acc[nt][r];
}

// ---------- K2: per-channel sum / sumsq over 64000 rows ----------
__global__ __launch_bounds__(512) void stats_k(const float* __restrict__ Wx,
                                               float* __restrict__ sums) {
  const int h = threadIdx.x;
  const size_t r0 = (size_t)blockIdx.x * 500;  // 128 blocks * 500 rows
  const float* base = Wx + r0 * kH + h;
  float s = 0.f, q = 0.f;
  for (int r = 0; r < 500; ++r) {
    const float v = base[(size_t)r * kH];
    s += v;
    q += v * v;
  }
  atomicAdd(&sums[h], s);
  atomicAdd(&sums[kH + h], q);
}

// ---------- K3: finalize BN scale/shift + alpha-derived params ----------
// prm layout: [0]=scale [512]=shift [1024]=a [1536]=1-a [2048]=a^L
__global__ __launch_bounds__(512) void finalize_k(const float* __restrict__ sums,
                                                  const float* __restrict__ alpha,
                                                  const float* __restrict__ gamma,
                                                  const float* __restrict__ beta,
                                                  float* __restrict__ prm) {
  const int h = threadIdx.x;
  const float inv_n = 1.0f / (float)kM;
  const float mean = sums[h] * inv_n;
  const float var = sums[kH + h] * inv_n - mean * mean;
  const float sc = gamma[h] * rsqrtf(var + 1e-5f);
  const float sh = beta[h] - mean * sc;
  const float a = fminf(fmaxf(alpha[h], kALo), kAHi);
  const float a2 = a * a, a4 = a2 * a2, a5 = a4 * a;
  const float a10 = a5 * a5, a20 = a10 * a10;  // a^kL with kL=20
  prm[h] = sc;
  prm[kH + h] = sh;
  prm[2 * kH + h] = a;
  prm[3 * kH + h] = 1.0f - a;
  prm[4 * kH + h] = a20;
}

// ---------- K4: per-chunk aggregate v_c = (1-a) * sum_i a^(L-1-i) * wxn_i ----------
__global__ __launch_bounds__(512) void chunk_agg_k(const float* __restrict__ Wx,
                                                   const float* __restrict__ prm,
                                                   float* __restrict__ vbuf) {
  const int bc = blockIdx.x;           // b*kC + c
  const int b = bc / kC, c = bc % kC;
  const int h = threadIdx.x;
  const float sc = prm[h], sh = prm[kH + h];
  const float a = prm[2 * kH + h], oma = prm[3 * kH + h];
  const float* base = Wx + ((size_t)b * kT + (size_t)c * kL) * kH + h;
  float v = 0.f;
#pragma unroll
  for (int i = 0; i < kL; ++i) {
    const float w = base[(size_t)i * kH] * sc + sh;
    v = a * v + oma * w;
  }
  vbuf[(size_t)bc * kH + h] = v;
}

// ---------- K5: sequential scan over chunk boundaries (in-place: vbuf -> ustart) ----------
__global__ __launch_bounds__(512) void chunk_scan_k(const float* __restrict__ ut0,
                                                    const float* __restrict__ prm,
                                                    float* __restrict__ vbuf) {
  const int b = blockIdx.x;
  const int h = threadIdx.x;
  const float aL = prm[4 * kH + h];
  float u = ut0[(size_t)b * kH + h];
  for (int c = 0; c < kC; ++c) {
    float* p = vbuf + ((size_t)b * kC + c) * kH + h;
    const float vc = *p;
    *p = u;         // ustart for this chunk
    u = aL * u + vc;
  }
}

// ---------- K6: per-chunk softmax accumulation ----------
__global__ __launch_bounds__(512) void chunk_soft_k(const float* __restrict__ Wx,
                                                    const float* __restrict__ prm,
                                                    const float* __restrict__ ustart,
                                                    float* __restrict__ accp) {
  __shared__ float tile[kL][kH];  // exp(ut) tile; writes/reads conflict-free
  __shared__ float zinv[kL];
  const int bc = blockIdx.x;
  const int b = bc / kC, c = bc % kC;
  const int h = threadIdx.x;
  const float sc = prm[h], sh = prm[kH + h];
  const float a = prm[2 * kH + h], oma = prm[3 * kH + h];
  float u = ustart[(size_t)bc * kH + h];
  const float* base = Wx + ((size_t)b * kT + (size_t)c * kL) * kH + h;
  float e[kL];
#pragma unroll
  for (int i = 0; i < kL; ++i) {
    const float w = base[(size_t)i * kH] * sc + sh;
    u = a * u + oma * w;
    e[i] = __expf(u);  // |u| <~ 2 after BN + EWMA damping: no max-subtract needed
    tile[i][h] = e[i];
  }
  __syncthreads();
  const int wave = h >> 6, lane = h & 63;
  for (int i = wave; i < kL; i += 8) {
    float s = 0.f;
#pragma unroll
    for (int j = 0; j < kH / 64; ++j) s += tile[i][lane + j * 64];
#pragma unroll
    for (int off = 32; off > 0; off >>= 1) s += __shfl_down(s, off);
    if (lane == 0) zinv[i] = 1.0f / s;
  }
  __syncthreads();
  float acc = 0.f;
#pragma unroll
  for (int i = 0; i < kL; ++i) acc += e[i] * zinv[i];
  accp[(size_t)bc * kH + h] = acc;
}

// ---------- K7: reduce partial accumulators over chunks ----------
__global__ __launch_bounds__(512) void final_reduce_k(const float* __restrict__ accp,
                                                      float* __restrict__ out) {
  const int b = blockIdx.x;
  const int h = threadIdx.x;
  float s = 0.f;
  for (int c = 0; c < kC; ++c) s += accp[((size_t)b * kC + c) * kH + h];
  out[(size_t)b * kH + h] = s;
}

}  // namespace

extern "C" void kernel_launch(void* const* d_in, const int* in_sizes, int n_in,
                              void* d_out, int out_size, void* d_ws, size_t ws_size,
                              hipStream_t stream) {
  const float* x = (const float*)d_in[0];      // [32,2000,512]
  const float* Wm = (const float*)d_in[1];     // [512,512]
  // d_in[2] = b: unused — BN mean subtraction cancels the bias exactly
  const float* alpha = (const float*)d_in[3];  // [512]
  const float* gamma = (const float*)d_in[4];  // [512]
  const float* beta = (const float*)d_in[5];   // [512]
  const float* ut0 = (const float*)d_in[6];    // [32,512]
  float* out = (float*)d_out;                  // [32,1,512]

  float* w = (float*)d_ws;
  float* Wx = w;                                   // 32,768,000 f
  float* vbuf = Wx + (size_t)kM * kH;              // 1,638,400 f
  float* accp = vbuf + (size_t)kB * kC * kH;       // 1,638,400 f
  float* sums = accp + (size_t)kB * kC * kH;       // 1,024 f
  float* prm = sums + 2 * kH;                      // 2,560 f
  // total ~137.5 MiB of ws

  hipMemsetAsync(sums, 0, 2 * kH * sizeof(float), stream);
  gemm_k<<<dim3(kM / 64, kH / 64), 256, 0, stream>>>(x, Wm, Wx);
  stats_k<<<128, 512, 0, stream>>>(Wx, sums);
  finalize_k<<<1, 512, 0, stream>>>(sums, alpha, gamma, beta, prm);
  chunk_agg_k<<<kB * kC, 512, 0, stream>>>(Wx, prm, vbuf);
  chunk_scan_k<<<kB, 512, 0, stream>>>(ut0, prm, vbuf);
  chunk_soft_k<<<kB * kC, 512, 0, stream>>>(Wx, prm, vbuf, accp);
  final_reduce_k<<<kB, 512, 0, stream>>>(accp, out);
}

// Round 2
// 419.200 us; speedup vs baseline: 1.0497x; 1.0497x over previous
//
#include <hip/hip_runtime.h>
#include <hip/hip_bf16.h>

// ReadoutLayer: Wx = x @ W^T (+b cancels under BN), BatchNorm(train) over B*T,
// then ut = a*ut + (1-a)*wxn per t with acc += softmax(ut, axis=H).
// R2: full-H row-strip GEMM (X fetched once), 32x32x16 MFMA, bf16 W pre-convert,
// BN stats fused into GEMM epilogue, Wx stored bf16, softmax accumulates into out.

namespace {
constexpr int kB = 32;
constexpr int kT = 2000;
constexpr int kD = 512;
constexpr int kH = 512;
constexpr int kM = kB * kT;   // 64000 rows
constexpr int kL = 20;        // chunk length
constexpr int kC = kT / kL;   // 100 chunks per batch
constexpr float kALo = 0.81873075307798182f;  // exp(-1/5)
constexpr float kAHi = 0.96078943915232320f;  // exp(-1/25)
constexpr int kPad = 40;      // LDS row stride (els) — breaks pow2 bank aliasing, 16B-aligned

typedef __bf16 bf16x8 __attribute__((ext_vector_type(8)));
typedef float floatx16 __attribute__((ext_vector_type(16)));

// ---------- K0: W f32 -> bf16 (once; L2-resident for the GEMM) ----------
__global__ __launch_bounds__(256) void wcvt_k(const float* __restrict__ W,
                                              __bf16* __restrict__ Wbf) {
  const int t = blockIdx.x * 256 + threadIdx.x;  // 128 blocks x 256 thr x 8 els
  const float4 a0 = ((const float4*)W)[t * 2];
  const float4 a1 = ((const float4*)W)[t * 2 + 1];
  bf16x8 v;
  v[0] = (__bf16)a0.x; v[1] = (__bf16)a0.y; v[2] = (__bf16)a0.z; v[3] = (__bf16)a0.w;
  v[4] = (__bf16)a1.x; v[5] = (__bf16)a1.y; v[6] = (__bf16)a1.z; v[7] = (__bf16)a1.w;
  *(bf16x8*)(Wbf + (size_t)t * 8) = v;
}

// ---------- K1: GEMM 64 rows x full 512 cols per block + fused BN stats ----------
// 512 threads = 8 waves; wave w: row-tile rt=w>>2 (32 rows), col-tiles (w&3)*4..+4.
__global__ __launch_bounds__(512, 4) void gemm_k(const float* __restrict__ X,
                                                 const __bf16* __restrict__ Wbf,
                                                 unsigned short* __restrict__ Wxb,
                                                 float* __restrict__ sums) {
  __shared__ __bf16 As[64][kPad];    // [m][k] 32-k slab
  __shared__ __bf16 Bs[512][kPad];   // [n][k] 32-k slab
  __shared__ float sred[2][kH];
  const int tid = threadIdx.x;
  const size_t row0 = (size_t)blockIdx.x * 64;
  const int w = tid >> 6, L = tid & 63;
  const int rt = w >> 2;             // 0/1
  const int ct0 = (w & 3) * 4;       // col-tile base
  const int lhalf = L >> 5, l32 = L & 31;
  // staging roles
  const int arow = tid >> 2, akq = tid & 3;  // A: threads 0..255, 8 f32 each
  const int bn0 = tid >> 2, bkq = tid & 3;   // B: 4 passes of 128 rows, 16 B each

  floatx16 acc[4] = {};
  float a_r[8];
  uint4 b_r[4];

  auto load_slab = [&](int kk) {
    if (tid < 256) {
      const float4* pa = (const float4*)(X + (row0 + arow) * kD + kk + akq * 8);
      const float4 x0 = pa[0], x1 = pa[1];
      a_r[0] = x0.x; a_r[1] = x0.y; a_r[2] = x0.z; a_r[3] = x0.w;
      a_r[4] = x1.x; a_r[5] = x1.y; a_r[6] = x1.z; a_r[7] = x1.w;
    }
#pragma unroll
    for (int j = 0; j < 4; ++j) {
      const int n = j * 128 + bn0;
      b_r[j] = *(const uint4*)(Wbf + (size_t)n * kD + kk + bkq * 8);
    }
  };
  auto store_slab = [&]() {
    if (tid < 256) {
      bf16x8 v;
#pragma unroll
      for (int j = 0; j < 8; ++j) v[j] = (__bf16)a_r[j];
      *(bf16x8*)&As[arow][akq * 8] = v;
    }
#pragma unroll
    for (int j = 0; j < 4; ++j)
      *(uint4*)&Bs[j * 128 + bn0][bkq * 8] = b_r[j];
  };

  load_slab(0);
#pragma unroll 1
  for (int s = 0; s < 16; ++s) {
    store_slab();
    __syncthreads();
    if (s < 15) load_slab((s + 1) * 32);  // prefetch overlaps MFMA phase
#pragma unroll
    for (int kh = 0; kh < 2; ++kh) {
      const bf16x8 af = *(const bf16x8*)&As[rt * 32 + l32][kh * 16 + lhalf * 8];
#pragma unroll
      for (int c = 0; c < 4; ++c) {
        const bf16x8 bfr = *(const bf16x8*)&Bs[(ct0 + c) * 32 + l32][kh * 16 + lhalf * 8];
        acc[c] = __builtin_amdgcn_mfma_f32_32x32x16_bf16(af, bfr, acc[c], 0, 0, 0);
      }
    }
    __syncthreads();
  }

  // ---- epilogue 1: column sums/sumsq for BN stats (f32 acc, exact rows 64) ----
  sred[0][tid] = 0.f;
  sred[1][tid] = 0.f;
  __syncthreads();
#pragma unroll
  for (int c = 0; c < 4; ++c) {
    float s = 0.f, q = 0.f;
#pragma unroll
    for (int r = 0; r < 16; ++r) {
      const float v = acc[c][r];
      s += v;
      q += v * v;
    }
    s += __shfl_xor(s, 32);
    q += __shfl_xor(q, 32);
    if (lhalf == 0) {
      atomicAdd(&sred[0][(ct0 + c) * 32 + l32], s);
      atomicAdd(&sred[1][(ct0 + c) * 32 + l32], q);
    }
  }
  // ---- epilogue 2: store Wx as bf16, packed pairs via shfl ----
  // C/D layout (32x32): col = lane&31, row = 4*(lane>>5) + (reg&3) + 8*(reg>>2)
#pragma unroll
  for (int c = 0; c < 4; ++c) {
    const int col = (ct0 + c) * 32 + l32;
#pragma unroll
    for (int r = 0; r < 16; ++r) {
      const int row = rt * 32 + 4 * lhalf + (r & 3) + 8 * (r >> 2);
      const unsigned short u = __builtin_bit_cast(unsigned short, (__bf16)acc[c][r]);
      const unsigned un = __shfl_down((unsigned)u, 1);
      if ((l32 & 1) == 0)
        *(unsigned*)(Wxb + (row0 + row) * (size_t)kH + col) = (unsigned)u | (un << 16);
    }
  }
  __syncthreads();
  atomicAdd(&sums[tid], sred[0][tid]);
  atomicAdd(&sums[kH + tid], sred[1][tid]);
}

// ---------- K2: finalize BN scale/shift + alpha-derived params ----------
// prm: [0]=scale [512]=shift [1024]=a [1536]=1-a [2048]=a^L
__global__ __launch_bounds__(512) void finalize_k(const float* __restrict__ sums,
                                                  const float* __restrict__ alpha,
                                                  const float* __restrict__ gamma,
                                                  const float* __restrict__ beta,
                                                  float* __restrict__ prm) {
  const int h = threadIdx.x;
  const float inv_n = 1.0f / (float)kM;
  const float mean = sums[h] * inv_n;
  const float var = sums[kH + h] * inv_n - mean * mean;
  const float sc = gamma[h] * rsqrtf(var + 1e-5f);
  const float sh = beta[h] - mean * sc;
  const float a = fminf(fmaxf(alpha[h], kALo), kAHi);
  const float a2 = a * a, a4 = a2 * a2, a5 = a4 * a;
  const float a10 = a5 * a5, a20 = a10 * a10;
  prm[h] = sc;
  prm[kH + h] = sh;
  prm[2 * kH + h] = a;
  prm[3 * kH + h] = 1.0f - a;
  prm[4 * kH + h] = a20;
}

// ---------- K3: per-chunk aggregate v_c ----------
__global__ __launch_bounds__(512) void chunk_agg_k(const __hip_bfloat16* __restrict__ Wxb,
                                                   const float* __restrict__ prm,
                                                   float* __restrict__ vbuf) {
  const int bc = blockIdx.x;
  const int b = bc / kC, c = bc % kC;
  const int h = threadIdx.x;
  const float sc = prm[h], sh = prm[kH + h];
  const float a = prm[2 * kH + h], oma = prm[3 * kH + h];
  const __hip_bfloat16* base = Wxb + ((size_t)b * kT + (size_t)c * kL) * kH + h;
  float v = 0.f;
#pragma unroll
  for (int i = 0; i < kL; ++i) {
    const float wv = __bfloat162float(base[(size_t)i * kH]) * sc + sh;
    v = a * v + oma * wv;
  }
  vbuf[(size_t)bc * kH + h] = v;
}

// ---------- K4: sequential scan over chunk boundaries (vbuf -> ustart, in place) ----------
__global__ __launch_bounds__(512) void chunk_scan_k(const float* __restrict__ ut0,
                                                    const float* __restrict__ prm,
                                                    float* __restrict__ vbuf) {
  const int b = blockIdx.x;
  const int h = threadIdx.x;
  const float aL = prm[4 * kH + h];
  float u = ut0[(size_t)b * kH + h];
#pragma unroll 4
  for (int c = 0; c < kC; ++c) {
    float* p = vbuf + ((size_t)b * kC + c) * kH + h;
    const float vc = *p;
    *p = u;
    u = aL * u + vc;
  }
}

// ---------- K5: per-chunk softmax accumulation -> atomic into out ----------
__global__ __launch_bounds__(512) void chunk_soft_k(const __hip_bfloat16* __restrict__ Wxb,
                                                    const float* __restrict__ prm,
                                                    const float* __restrict__ ustart,
                                                    float* __restrict__ out) {
  __shared__ float tile[kL][kH];
  __shared__ float zinv[kL];
  const int bc = blockIdx.x;
  const int b = bc / kC, c = bc % kC;
  const int h = threadIdx.x;
  const float sc = prm[h], sh = prm[kH + h];
  const float a = prm[2 * kH + h], oma = prm[3 * kH + h];
  float u = ustart[(size_t)bc * kH + h];
  const __hip_bfloat16* base = Wxb + ((size_t)b * kT + (size_t)c * kL) * kH + h;
  float e[kL];
#pragma unroll
  for (int i = 0; i < kL; ++i) {
    const float wv = __bfloat162float(base[(size_t)i * kH]) * sc + sh;
    u = a * u + oma * wv;
    e[i] = __expf(u);  // |u| small after BN+EWMA: no max-subtract needed
    tile[i][h] = e[i];
  }
  __syncthreads();
  const int wave = h >> 6, lane = h & 63;
  for (int i = wave; i < kL; i += 8) {
    float s = 0.f;
#pragma unroll
    for (int j = 0; j < kH / 64; ++j) s += tile[i][lane + j * 64];
#pragma unroll
    for (int off = 32; off > 0; off >>= 1) s += __shfl_down(s, off);
    if (lane == 0) zinv[i] = 1.0f / s;
  }
  __syncthreads();
  float acc = 0.f;
#pragma unroll
  for (int i = 0; i < kL; ++i) acc += e[i] * zinv[i];
  atomicAdd(&out[(size_t)b * kH + h], acc);
}

}  // namespace

extern "C" void kernel_launch(void* const* d_in, const int* in_sizes, int n_in,
                              void* d_out, int out_size, void* d_ws, size_t ws_size,
                              hipStream_t stream) {
  const float* x = (const float*)d_in[0];      // [32,2000,512]
  const float* Wm = (const float*)d_in[1];     // [512,512]
  // d_in[2] = b: unused — BN mean subtraction cancels the bias exactly
  const float* alpha = (const float*)d_in[3];
  const float* gamma = (const float*)d_in[4];
  const float* beta = (const float*)d_in[5];
  const float* ut0 = (const float*)d_in[6];
  float* out = (float*)d_out;                  // [32,1,512]

  float* w = (float*)d_ws;
  float* vbuf = w;                             // 32*100*512 = 1,638,400 f
  float* sums = vbuf + (size_t)kB * kC * kH;   // 1024 f
  float* prm = sums + 2 * kH;                  // 2560 f
  __bf16* Wbf = (__bf16*)(prm + 5 * kH);       // 262,144 bf16
  unsigned short* Wxb = (unsigned short*)(Wbf + (size_t)kH * kD);  // 32.768M bf16 = 65.5 MB

  hipMemsetAsync(sums, 0, 2 * kH * sizeof(float), stream);
  hipMemsetAsync(out, 0, (size_t)kB * kH * sizeof(float), stream);
  wcvt_k<<<128, 256, 0, stream>>>(Wm, Wbf);
  gemm_k<<<kM / 64, 512, 0, stream>>>(x, Wbf, Wxb, sums);
  finalize_k<<<1, 512, 0, stream>>>(sums, alpha, gamma, beta, prm);
  chunk_agg_k<<<kB * kC, 512, 0, stream>>>((const __hip_bfloat16*)Wxb, prm, vbuf);
  chunk_scan_k<<<kB, 512, 0, stream>>>(ut0, prm, vbuf);
  chunk_soft_k<<<kB * kC, 512, 0, stream>>>((const __hip_bfloat16*)Wxb, prm, vbuf, out);
}